// Round 8
// baseline (560.276 us; speedup 1.0000x reference)
//
#include <hip/hip_runtime.h>

// GraphSSM: h_t = A*h_{t-1} + B*x_t ; y_t = sum_s(C*h_t) + D*x_t   (diagonal SISO)
// Strength-reduced: g_t = A*g_{t-1} + x_t ; y_t = sum_s (C*B)*g_t + D*x_t
//
// Round 5 resubmit #3 (broker timeouts): removes three latency/path suspects:
//   (1) drop non-temporal stores (unproven, bypasses the proven L2 write path)
//   (2) ping-pong double buffer (no xb=xn copies -> no per-chunk vmcnt drain)
//   (3) 2 channels/thread with float2 loads/stores (8B/lane: half the memory
//       instructions, 2x bytes in flight per wave)

constexpr int T_STEPS = 64;
constexpr int DIM = 128;
constexpr int DSTATE = 16;
constexpr int CH = 4;                 // timesteps per buffer
constexpr int S_FIX = 10000 * 128;    // N*DIM

template <int S>
__global__ __launch_bounds__(256) void graph_ssm_kernel2(
    const float* __restrict__ seq,   // [T, S]
    const float* __restrict__ A,     // [DIM, DSTATE]
    const float* __restrict__ B,     // [DIM, DSTATE]
    const float* __restrict__ C,     // [DIM, DSTATE]
    const float* __restrict__ Dp,    // [DIM]
    float* __restrict__ out)         // [T, S]
{
    constexpr int S2 = S / 2;        // float2 elements per timestep row
    const int tid = blockIdx.x * blockDim.x + threadIdx.x;  // one float2 lane-pair
    if (tid >= S2) return;
    const int d0 = (tid * 2) & (DIM - 1);   // even channel; pair is (d0, d0+1)

    float a[2][DSTATE], cb[2][DSTATE], g[2][DSTATE];
#pragma unroll
    for (int c = 0; c < 2; ++c) {
#pragma unroll
        for (int s = 0; s < DSTATE; ++s) {
            a[c][s]  = A[(d0 + c) * DSTATE + s];
            cb[c][s] = C[(d0 + c) * DSTATE + s] * B[(d0 + c) * DSTATE + s];
            g[c][s]  = 0.0f;
        }
    }
    float dd0 = Dp[d0], dd1 = Dp[d0 + 1];

    // Pin params in VGPRs (prevent rematerialization inside the t-loop).
#pragma unroll
    for (int c = 0; c < 2; ++c)
#pragma unroll
        for (int s = 0; s < DSTATE; ++s)
            asm volatile("" : "+v"(a[c][s]), "+v"(cb[c][s]));
    asm volatile("" : "+v"(dd0), "+v"(dd1));

    const float2* sp = reinterpret_cast<const float2*>(seq) + tid;  // [t][S2]
    float2* op = reinterpret_cast<float2*>(out) + tid;

    auto step = [&](int t, float2 x) {
        // 2-way split accumulator per channel (same pairing as R1-R4 numerics)
        float y00 = dd0 * x.x, y01 = 0.f;
        float y10 = dd1 * x.y, y11 = 0.f;
#pragma unroll
        for (int s = 0; s < DSTATE; s += 2) {
            g[0][s]     = fmaf(a[0][s],     g[0][s],     x.x);
            y00         = fmaf(cb[0][s],    g[0][s],     y00);
            g[0][s + 1] = fmaf(a[0][s + 1], g[0][s + 1], x.x);
            y01         = fmaf(cb[0][s + 1], g[0][s + 1], y01);
            g[1][s]     = fmaf(a[1][s],     g[1][s],     x.y);
            y10         = fmaf(cb[1][s],    g[1][s],     y10);
            g[1][s + 1] = fmaf(a[1][s + 1], g[1][s + 1], x.y);
            y11         = fmaf(cb[1][s + 1], g[1][s + 1], y11);
        }
        op[(size_t)t * S2] = make_float2(y00 + y01, y10 + y11);  // plain store
    };

    float2 bufA[CH], bufB[CH];
    auto loadTo = [&](float2* buf, int t0) {
#pragma unroll
        for (int j = 0; j < CH; ++j) buf[j] = sp[(size_t)(t0 + j) * S2];
    };
    auto compute = [&](float2* buf, int t0) {
#pragma unroll
        for (int j = 0; j < CH; ++j) step(t0 + j, buf[j]);
    };

    // Ping-pong: loads for the next buffer are issued before computing the
    // current one; no register copies -> no forced full vmcnt drain per chunk.
    loadTo(bufA, 0);
#pragma unroll 1
    for (int k = 0; k < T_STEPS / (2 * CH) - 1; ++k) {   // k = 0..6
        loadTo(bufB, 8 * k + 4);
        compute(bufA, 8 * k);
        loadTo(bufA, 8 * k + 8);
        compute(bufB, 8 * k + 4);
    }
    loadTo(bufB, T_STEPS - CH);
    compute(bufA, T_STEPS - 2 * CH);
    compute(bufB, T_STEPS - CH);
}

// Runtime-S fallback (scalar, simple prefetch) in case sizes ever differ.
__global__ __launch_bounds__(256) void graph_ssm_kernel_dyn(
    const float* __restrict__ seq, const float* __restrict__ A,
    const float* __restrict__ B, const float* __restrict__ C,
    const float* __restrict__ Dp, float* __restrict__ out, int S)
{
    const int tid = blockIdx.x * blockDim.x + threadIdx.x;
    if (tid >= S) return;
    const int d = tid & (DIM - 1);
    float a[DSTATE], cb[DSTATE], g[DSTATE];
#pragma unroll
    for (int s = 0; s < DSTATE; ++s) {
        a[s]  = A[d * DSTATE + s];
        cb[s] = C[d * DSTATE + s] * B[d * DSTATE + s];
        g[s]  = 0.0f;
    }
    float dd = Dp[d];
    const float* sp = seq + tid;
    float* op = out + tid;
    float x = sp[0];
    for (int t = 0; t < T_STEPS; ++t) {
        float xnext = (t + 1 < T_STEPS) ? sp[(size_t)(t + 1) * S] : 0.f;
        float y0 = dd * x, y1 = 0.f;
#pragma unroll
        for (int s = 0; s < DSTATE; s += 2) {
            g[s + 0] = fmaf(a[s + 0], g[s + 0], x);
            y0 = fmaf(cb[s + 0], g[s + 0], y0);
            g[s + 1] = fmaf(a[s + 1], g[s + 1], x);
            y1 = fmaf(cb[s + 1], g[s + 1], y1);
        }
        op[(size_t)t * S] = y0 + y1;
        x = xnext;
    }
}

extern "C" void kernel_launch(void* const* d_in, const int* in_sizes, int n_in,
                              void* d_out, int out_size, void* d_ws, size_t ws_size,
                              hipStream_t stream) {
    const float* seq = (const float*)d_in[0];
    const float* A   = (const float*)d_in[1];
    const float* B   = (const float*)d_in[2];
    const float* C   = (const float*)d_in[3];
    const float* Dp  = (const float*)d_in[4];
    float* out = (float*)d_out;

    const int S = in_sizes[0] / T_STEPS;  // N*DIM
    const int block = 256;
    if (S == S_FIX) {
        const int grid = (S / 2 + block - 1) / block;
        graph_ssm_kernel2<S_FIX><<<grid, block, 0, stream>>>(seq, A, B, C, Dp, out);
    } else {
        const int grid = (S + block - 1) / block;
        graph_ssm_kernel_dyn<<<grid, block, 0, stream>>>(seq, A, B, C, Dp, out, S);
    }
}